// Round 3
// baseline (698.341 us; speedup 1.0000x reference)
//
#include <hip/hip_runtime.h>
#include <hip/hip_bf16.h>

#define N_ROWS 32768
#define K_CODES 4096
#define D_DIM 256
#define CAP 128
#define MARGIN_T 1e-3f
#define RB 8

// ---- d_ws layout (bytes) -- total 4,882,432 (< R1-proven ~5 MB) ----
#define WS_COUNTS    0          // float[4096]
#define WS_LOSSP     16384      // float[32768]
#define WS_IDX       147456     // int[32768]
#define WS_Z2        278528     // float[32768]
#define WS_E2        409600     // float[4096]
#define WS_RMAX      425984     // uint[32768]   (unused, kept for layout stability)
#define WS_CNT       557056     // int[32768]
#define WS_DW        688128     // float[1048576] -> ends 4882432

// ---- d_out scratch (d_out = 42.09 MB total; all regions rewritten later) ----
#define DO_ZB        0          // ushort[32768*256] = 16 MB
#define DO_WB        16777216   // ushort[4096*256]  =  2 MB
#define DO_CAND      18874368   // uint[32768*128]   = 16 MB -> ends 35651584

typedef __attribute__((ext_vector_type(8)))  short bf16x8;
typedef __attribute__((ext_vector_type(16))) float f32x16;
typedef __attribute__((ext_vector_type(8)))  unsigned short us8;

// ---------------------------------------------------------------------------
// K1: z2/e2 with numpy's exact pairwise structure (proven in R1)
// ---------------------------------------------------------------------------
__global__ void k1_norms(const float* __restrict__ z, const float* __restrict__ w,
                         float* __restrict__ z2, float* __restrict__ e2)
{
#pragma clang fp contract(off)
    int gid = blockIdx.x * blockDim.x + threadIdx.x;
    const float* row;
    float* outp;
    if (gid < N_ROWS) { row = z + (size_t)gid * D_DIM; outp = z2 + gid; }
    else if (gid < N_ROWS + K_CODES) { row = w + (size_t)(gid - N_ROWS) * D_DIM; outp = e2 + (gid - N_ROWS); }
    else return;

    float total = 0.0f;
    for (int half = 0; half < 2; half++) {
        const float* x = row + half * 128;
        float r[8];
#pragma unroll
        for (int j = 0; j < 8; j++) { float v = x[j]; r[j] = v * v; }
        for (int i = 8; i < 128; i += 8) {
#pragma unroll
            for (int j = 0; j < 8; j++) { float v = x[i + j]; r[j] += v * v; }
        }
        float s = ((r[0] + r[1]) + (r[2] + r[3])) + ((r[4] + r[5]) + (r[6] + r[7]));
        if (half == 0) total = s; else total = total + s;
    }
    *outp = total;
}

// ---------------------------------------------------------------------------
// KCONV: fp32 -> bf16 (RNE), 8 elems/thread. z then w.
// ---------------------------------------------------------------------------
__device__ inline unsigned short f2b(float f) {
    __hip_bfloat16 h = __float2bfloat16(f);
    return *(unsigned short*)&h;
}

__global__ void kconv(const float* __restrict__ z, const float* __restrict__ w,
                      unsigned short* __restrict__ zb, unsigned short* __restrict__ wb)
{
    size_t i = (size_t)(blockIdx.x * 256 + threadIdx.x) * 8;
    const float* src; unsigned short* dst;
    const size_t NZ = (size_t)N_ROWS * D_DIM;
    if (i < NZ) { src = z + i; dst = zb + i; }
    else        { size_t j = i - NZ; src = w + j; dst = wb + j; }
    float4 a = *(const float4*)src;
    float4 b = *(const float4*)(src + 4);
    us8 o;
    o[0] = f2b(a.x); o[1] = f2b(a.y); o[2] = f2b(a.z); o[3] = f2b(a.w);
    o[4] = f2b(b.x); o[5] = f2b(b.y); o[6] = f2b(b.z); o[7] = f2b(b.w);
    *(us8*)dst = o;
}

// ---------------------------------------------------------------------------
// async global->LDS, 16B per lane (proven R2 pattern: LDS dest is
// wave-uniform-base + lane*16, which our layout satisfies exactly).
// ---------------------------------------------------------------------------
__device__ inline void gload16(const void* g, void* l)
{
    __builtin_amdgcn_global_load_lds(
        (const __attribute__((address_space(1))) unsigned int*)g,
        (__attribute__((address_space(3))) unsigned int*)l,
        16, 0, 0);
}

// ---------------------------------------------------------------------------
// K2 v3: 256x256-tile bf16 MFMA GEMM t = W @ Z^T.
// 512 thr = 8 waves (2 code-waves x 4 row-waves); wave tile 128 codes x
// 64 rows = acc[4][2] f32x16. BK=32 double-buffered LDS (2 x 32KB):
// per barrier window each thread issues 4 gload_lds + 12 ds_read_b128 +
// 16 MFMA (m97-like ratios; old kernel was 8 gloads per 16 MFMA).
//
// Appends happen ONCE per block at the end: each block holds its full
// 256-code score tile, so the threshold is the block-local 256-code row
// max - MARGIN. Every code within MARGIN of the GLOBAL row max passes its
// own block's local threshold (local max <= global max), so the candidate
// set is a superset of the proven two-pass set; packed (key|code) entries
// let k_rescore recover the global bf16 max and re-filter exactly.
//
// XCD-bijective swizzle: all 16 code-blocks of a row-tile land on one XCD
// -> cnt/cand atomics are XCD-local, zb slice (2MB) + wb (2MB) L2-resident.
// ---------------------------------------------------------------------------
__global__ __launch_bounds__(512, 2) void k2_scan(
    const unsigned short* __restrict__ zb, const unsigned short* __restrict__ wb,
    int* __restrict__ cnt, unsigned int* __restrict__ cand)
{
    __shared__ char smem[65536];
    const int tid  = threadIdx.x;
    const int lane = tid & 63;
    const int wid  = tid >> 6;     // 0..7
    const int wm   = wid >> 2;     // code-wave 0..1
    const int wn   = wid & 3;      // row-wave 0..3
    const int m    = lane & 31;
    const int half = lane >> 5;

    // bijective XCD swizzle: logical o such that XCD(hw_id) == o/256
    const int r_hw = blockIdx.y * 16 + blockIdx.x;
    const int o    = (r_hw & 7) * 256 + (r_hw >> 3);
    const int cb   = o & 15;       // code-block 0..15
    const int rb   = o >> 4;       // row-block  0..127
    const int rowBase  = rb * 256;
    const int codeBase = cb * 256;

    // stage one BK=32 chunk: A = 256 codes x 32 d, B = 256 rows x 32 d.
    // unit (g=wid, s): LDS slot ((g*2+s)*64 + lane)*16, global row g*32+m,
    // col kBase + s*16 + half*8  -> per-wave LDS dest = base + lane*16.
    auto stage = [&](int kk, int buf) {
        char* Ab = smem + buf * 32768;
        char* Bb = Ab + 16384;
        const int kBase = kk * 32;
#pragma unroll
        for (int s = 0; s < 2; s++) {
            const int gcol = kBase + s * 16 + half * 8;
            const int arow = codeBase + wid * 32 + m;
            const int brow = rowBase + wid * 32 + m;
            gload16(wb + (size_t)arow * D_DIM + gcol,
                    Ab + (size_t)((wid * 2 + s) * 64 + lane) * 16);
            gload16(zb + (size_t)brow * D_DIM + gcol,
                    Bb + (size_t)((wid * 2 + s) * 64 + lane) * 16);
        }
    };

    f32x16 acc[4][2];
    {
        f32x16 zz = {};
#pragma unroll
        for (int ms = 0; ms < 4; ms++)
#pragma unroll
            for (int ns = 0; ns < 2; ns++) acc[ms][ns] = zz;
    }

    stage(0, 0);

    for (int kk = 0; kk < 8; kk++) {
        const int buf = kk & 1;
        __syncthreads();                       // drains vmcnt -> buf ready
        if (kk + 1 < 8) stage(kk + 1, buf ^ 1);
        const char* Ab = smem + buf * 32768;
        const char* Bb = Ab + 16384;
#pragma unroll
        for (int s = 0; s < 2; s++) {
            bf16x8 af[4], bfr[2];
#pragma unroll
            for (int ms = 0; ms < 4; ms++)
                af[ms] = *(const bf16x8*)(Ab + (size_t)(((wm * 4 + ms) * 2 + s) * 64 + lane) * 16);
#pragma unroll
            for (int ns = 0; ns < 2; ns++)
                bfr[ns] = *(const bf16x8*)(Bb + (size_t)(((wn * 2 + ns) * 2 + s) * 64 + lane) * 16);
#pragma unroll
            for (int ms = 0; ms < 4; ms++)
#pragma unroll
                for (int ns = 0; ns < 2; ns++)
                    acc[ms][ns] = __builtin_amdgcn_mfma_f32_32x32x16_bf16(
                        af[ms], bfr[ns], acc[ms][ns], 0, 0, 0);
        }
    }

    // ---- epilogue: block-local per-row max over all 256 codes ----
    float tmax[2] = {-1e30f, -1e30f};
#pragma unroll
    for (int ms = 0; ms < 4; ms++)
#pragma unroll
        for (int ns = 0; ns < 2; ns++)
#pragma unroll
            for (int r = 0; r < 16; r++)
                tmax[ns] = fmaxf(tmax[ns], acc[ms][ns][r]);
#pragma unroll
    for (int ns = 0; ns < 2; ns++)
        tmax[ns] = fmaxf(tmax[ns], __shfl_xor(tmax[ns], 32));

    __syncthreads();                 // GEMM LDS dead; reuse for rowmax
    float* rmx = (float*)smem;       // [2][256]: [wm][local row]
    if (lane < 32) {
        rmx[wm * 256 + wn * 64 + 0 * 32 + lane] = tmax[0];
        rmx[wm * 256 + wn * 64 + 1 * 32 + lane] = tmax[1];
    }
    __syncthreads();

    float thr[2];
#pragma unroll
    for (int ns = 0; ns < 2; ns++) {
        const int lr = wn * 64 + ns * 32 + m;
        thr[ns] = fmaxf(rmx[lr], rmx[256 + lr]) - MARGIN_T;
    }

    // ---- append keepers (once per block; atomics XCD-local by swizzle) ----
#pragma unroll
    for (int ms = 0; ms < 4; ms++)
#pragma unroll
        for (int ns = 0; ns < 2; ns++)
#pragma unroll
            for (int r = 0; r < 16; r++) {
                float v = acc[ms][ns][r];
                if (v >= thr[ns]) {
                    int code = codeBase + wm * 128 + ms * 32
                             + ((r & 3) + 8 * (r >> 2) + 4 * half);
                    int n = rowBase + wn * 64 + ns * 32 + m;
                    int b = __float_as_int(v);
                    unsigned key = (unsigned)b ^ ((unsigned)(b >> 31) | 0x80000000u);
                    unsigned entry = (key & 0xFFFFF000u) | (unsigned)code;
                    int slot = atomicAdd(&cnt[n], 1);
                    if (slot < CAP) cand[(size_t)n * CAP + slot] = entry;
                }
            }
}

// ---------------------------------------------------------------------------
// K_RESCORE v5: one WAVE per row.
// Phase A (filter): scan packed entries, wave-reduce max score key (== the
//   global bf16 row max, lower-bounded within 1.5e-5 by the 20-bit key
//   truncation), keep entries with score >= gm - MARGIN - 5e-5 (superset of
//   the proven two-pass candidate set), ballot-compact codes into LDS.
// Phase B: exact fp32 rescore of the few survivors (serial 256-FMA chain,
//   ascending d, single accumulator = bit-identical to BLAS sgemm),
//   lexicographic (d,k) tie-break. Fallback full 4096 scan if cnt out of
//   range (unchanged semantics).
// ---------------------------------------------------------------------------
__global__ __launch_bounds__(64) void k_rescore(
    const float* __restrict__ z, const float* __restrict__ w,
    const float* __restrict__ z2, const float* __restrict__ e2,
    const int* __restrict__ cnt, const unsigned int* __restrict__ cand,
    int* __restrict__ idx_out)
{
#pragma clang fp contract(off)
    const int lane = threadIdx.x;
    const int n    = blockIdx.x;

    __shared__ float4 wst[RB * 65];   // 8320 B, slot j at wst[j*65 + d4]
    __shared__ float4 zst[64];        // z row, 1 KB
    __shared__ int    surv[CAP];      // compacted survivor codes

    zst[lane] = ((const float4*)(z + (size_t)n * D_DIM))[lane];

    int c = cnt[n];
    const bool fallback = (c <= 0) || (c > CAP);
    int total;

    if (!fallback) {
        unsigned e0 = 0u, e1 = 0u;
        if (lane < c)      e0 = cand[(size_t)n * CAP + lane];
        if (lane + 64 < c) e1 = cand[(size_t)n * CAP + lane + 64];
        unsigned k0 = e0 & 0xFFFFF000u, k1 = e1 & 0xFFFFF000u;
        unsigned km = k0 > k1 ? k0 : k1;
#pragma unroll
        for (int off = 32; off > 0; off >>= 1) {
            unsigned o = __shfl_xor(km, off);
            km = o > km ? o : km;
        }
        // lower-bound float of the max key (truncation rounds toward -inf
        // in ordered space), minus margin + quantization slack
        int bm = (km & 0x80000000u) ? (int)(km ^ 0x80000000u) : (int)~km;
        const float thr = __int_as_float(bm) - MARGIN_T - 5e-5f;

        int tot = 0;
        for (int base = 0; base < c; base += 64) {
            unsigned e = (base == 0) ? e0 : e1;
            bool keep = false;
            if (base + lane < c) {
                unsigned ky = e & 0xFFFFF000u;
                int b = (ky & 0x80000000u) ? (int)(ky ^ 0x80000000u) : (int)~ky;
                keep = (__int_as_float(b) >= thr);
            }
            unsigned long long bal = __ballot(keep);
            int pos = tot + (int)__popcll(bal & ((1ull << lane) - 1ull));
            if (keep) surv[pos] = (int)(e & 0xFFFu);
            tot += (int)__popcll(bal);
        }
        total = tot;          // >= 1 (the max-key entry always passes)
    } else {
        total = K_CODES;
    }
    __syncthreads();

    float bd = __builtin_inff(); int bk = K_CODES;
    const float z2v = z2[n];

    float4 regs[RB];
    auto load_regs = [&](int base) {
#pragma unroll
        for (int j = 0; j < RB; j++) {
            int s = base + j;
            int k = 0;
            if (s < total) k = fallback ? s : surv[s];
            regs[j] = ((const float4*)(w + (size_t)k * D_DIM))[lane];
        }
    };

    load_regs(0);
    for (int base = 0; base < total; base += RB) {
        int nb = total - base; if (nb > RB) nb = RB;
#pragma unroll
        for (int j = 0; j < RB; j++) wst[j * 65 + lane] = regs[j];
        if (base + RB < total) load_regs(base + RB);   // prefetch during chain
        __syncthreads();
        if (lane < nb) {
            int k = fallback ? (base + lane) : surv[base + lane];
            const float4* wp = &wst[lane * 65];
            float tacc = 0.0f;
#pragma unroll
            for (int d4 = 0; d4 < 64; d4++) {
                float4 wv = wp[d4];
                float4 zv = zst[d4];
                tacc = __builtin_fmaf(zv.x, wv.x, tacc);
                tacc = __builtin_fmaf(zv.y, wv.y, tacc);
                tacc = __builtin_fmaf(zv.z, wv.z, tacc);
                tacc = __builtin_fmaf(zv.w, wv.w, tacc);
            }
            float u  = z2v - 2.0f * tacc;   // 2*tacc exact -> single rounding
            float dv = u + e2[k];
            if (dv < bd || (dv == bd && k < bk)) { bd = dv; bk = k; }
        }
        __syncthreads();
    }

#pragma unroll
    for (int off = 1; off < 64; off <<= 1) {
        float od = __shfl_xor(bd, off);
        int   ok = __shfl_xor(bk, off);
        if (od < bd || (od == bd && ok < bk)) { bd = od; bk = ok; }
    }
    if (lane == 0) idx_out[n] = bk;
}

// ---------------------------------------------------------------------------
// K3: gather z_q, STE output, loss partials, counts + dw atomics.
// ---------------------------------------------------------------------------
__global__ void k3_scatter(const float* __restrict__ z, const float* __restrict__ w,
                           const int* __restrict__ idx_in,
                           float* __restrict__ counts, float* __restrict__ lossp,
                           float* __restrict__ dw, float* __restrict__ out_zq,
                           float* __restrict__ out_idx)
{
#pragma clang fp contract(off)
    const int n = blockIdx.x;
    const int t = threadIdx.x;
    int idx = idx_in[n];
    if (idx < 0) idx = 0;
    if (idx >= K_CODES) idx = K_CODES - 1;     // defensive clamp (no fault)
    if (t == 0) {
        out_idx[n] = (float)idx;
        atomicAdd(&counts[idx], 1.0f);
    }
    float zv = z[(size_t)n * D_DIM + t];
    float wq = w[(size_t)idx * D_DIM + t];
    out_zq[(size_t)n * D_DIM + t] = zv + (wq - zv);
    float df = zv - wq;
    float sq = df * df;
    atomicAdd(&dw[(size_t)idx * D_DIM + t], zv);

    __shared__ float red[256];
    red[t] = sq; __syncthreads();
    for (int s = 128; s > 0; s >>= 1) {
        if (t < s) red[t] += red[t + s];
        __syncthreads();
    }
    if (t == 0) lossp[n] = red[0];
}

// ---------------------------------------------------------------------------
// K4: vq_loss finalize + new_cs (Laplace smoothing). Single block, 1024 thr.
// ---------------------------------------------------------------------------
__global__ void k4_cs(const float* __restrict__ lossp, const float* __restrict__ counts,
                      const float* __restrict__ cs_in, float* __restrict__ out_loss,
                      float* __restrict__ out_cs)
{
#pragma clang fp contract(off)
    const int t = threadIdx.x;
    __shared__ float red[1024];
    __shared__ float pre[K_CODES];

    float s = 0.0f;
    for (int i = t; i < N_ROWS; i += 1024) s += lossp[i];
    red[t] = s; __syncthreads();
    for (int st = 512; st > 0; st >>= 1) {
        if (t < st) red[t] += red[t + st];
        __syncthreads();
    }
    if (t == 0) out_loss[0] = 0.25f * (red[0] / 8388608.0f);
    __syncthreads();

    const float DEC = 0.99f;
    const float OMD = (float)(1.0 - 0.99);
    float mine[4];
#pragma unroll
    for (int q = 0; q < 4; q++) {
        int k = t + q * 1024;
        float t1 = DEC * cs_in[k];
        float t2 = OMD * counts[k];
        float p = t1 + t2;
        pre[k] = p; mine[q] = p;
    }
    float psum = (mine[0] + mine[1]) + (mine[2] + mine[3]);
    red[t] = psum; __syncthreads();
    for (int st = 512; st > 0; st >>= 1) {
        if (t < st) red[t] += red[t + st];
        __syncthreads();
    }
    float nsum = red[0];
    const float KEPS = (float)(4096.0 * 1e-5);
    float denom = nsum + KEPS;
#pragma unroll
    for (int q = 0; q < 4; q++) {
        int k = t + q * 1024;
        float v = ((pre[k] + 1e-5f) / denom) * nsum;
        out_cs[k] = v;
    }
}

// ---------------------------------------------------------------------------
// K5: new_ema_w = 0.99*ema_w + 0.01*dw ; new_weight = new_ema_w / new_cs[k]
// ---------------------------------------------------------------------------
__global__ void k5_emaw(const float* __restrict__ ema_w, const float* __restrict__ dw,
                        const float* __restrict__ newcs, float* __restrict__ out_w,
                        float* __restrict__ out_emaw)
{
#pragma clang fp contract(off)
    const int i = blockIdx.x * 256 + threadIdx.x;
    const int k = i >> 8;
    const float OMD = (float)(1.0 - 0.99);
    float t1 = 0.99f * ema_w[i];
    float t2 = OMD * dw[i];
    float ne = t1 + t2;
    out_emaw[i] = ne;
    out_w[i] = ne / newcs[k];
}

extern "C" void kernel_launch(void* const* d_in, const int* in_sizes, int n_in,
                              void* d_out, int out_size, void* d_ws, size_t ws_size,
                              hipStream_t stream)
{
    const float* z    = (const float*)d_in[0];
    const float* w    = (const float*)d_in[1];
    const float* cs   = (const float*)d_in[2];
    const float* emaw = (const float*)d_in[3];

    float* out      = (float*)d_out;
    float* out_zq   = out;                    // 8388608
    float* out_idx  = out + 8388608;          // 32768
    float* out_loss = out + 8421376;          // 1
    float* out_w    = out + 8421377;          // 1048576
    float* out_cs   = out + 9469953;          // 4096
    float* out_emaw = out + 9474049;          // 1048576

    char* ws = (char*)d_ws;
    float*          counts  = (float*)(ws + WS_COUNTS);
    float*          lossp   = (float*)(ws + WS_LOSSP);
    int*            idx_int = (int*)  (ws + WS_IDX);
    float*          z2      = (float*)(ws + WS_Z2);
    float*          e2      = (float*)(ws + WS_E2);
    int*            cnt     = (int*)  (ws + WS_CNT);
    float*          dw      = (float*)(ws + WS_DW);

    // big scratch lives in d_out (fully rewritten by k3/k4/k5 afterwards)
    char* ob = (char*)d_out;
    unsigned short* zb   = (unsigned short*)(ob + DO_ZB);
    unsigned short* wb   = (unsigned short*)(ob + DO_WB);
    unsigned int*   cand = (unsigned int*)  (ob + DO_CAND);

    hipMemsetAsync(counts, 0, K_CODES * sizeof(float), stream);
    hipMemsetAsync(dw, 0, (size_t)K_CODES * D_DIM * sizeof(float), stream);
    hipMemsetAsync(cnt, 0, N_ROWS * sizeof(int), stream);

    k1_norms<<<(N_ROWS + K_CODES) / 256, 256, 0, stream>>>(z, w, z2, e2);
    kconv<<<(N_ROWS + K_CODES) * D_DIM / (256 * 8), 256, 0, stream>>>(z, w, zb, wb);

    dim3 g2(16, 128);   // x = code-block, y = row-block (swizzled in-kernel)
    k2_scan<<<g2, 512, 0, stream>>>(zb, wb, cnt, cand);

    k_rescore<<<N_ROWS, 64, 0, stream>>>(z, w, z2, e2, cnt, cand, idx_int);

    k3_scatter<<<N_ROWS, 256, 0, stream>>>(z, w, idx_int, counts, lossp,
                                           dw, out_zq, out_idx);

    k4_cs<<<1, 1024, 0, stream>>>(lossp, counts, cs, out_loss, out_cs);

    k5_emaw<<<K_CODES, 256, 0, stream>>>(emaw, dw, out_cs, out_w, out_emaw);
}

// Round 4
// 643.442 us; speedup vs baseline: 1.0853x; 1.0853x over previous
//
#include <hip/hip_runtime.h>
#include <hip/hip_bf16.h>

#define N_ROWS 32768
#define K_CODES 4096
#define D_DIM 256
#define CAP 128
#define MARGIN_T 1e-3f
#define RB 8

// ---- d_ws layout (bytes) -- total 4,882,432 (< R1-proven ~5 MB) ----
#define WS_COUNTS    0          // float[4096]
#define WS_LOSSP     16384      // float[32768]
#define WS_IDX       147456     // int[32768]
#define WS_Z2        278528     // float[32768]
#define WS_E2        409600     // float[4096]
#define WS_RMAX      425984     // uint[32768]   (unused, kept for layout stability)
#define WS_CNT       557056     // int[32768]
#define WS_DW        688128     // float[1048576] -> ends 4882432

// ---- d_out scratch (d_out = 42.09 MB total; all regions rewritten later) ----
#define DO_ZB        0          // ushort[32768*256] = 16 MB (panel layout)
#define DO_WB        16777216   // ushort[4096*256]  =  2 MB (panel layout)
#define DO_CAND      18874368   // uint[32768*128]   = 16 MB -> ends 35651584

typedef __attribute__((ext_vector_type(8)))  short bf16x8;
typedef __attribute__((ext_vector_type(16))) float f32x16;
typedef __attribute__((ext_vector_type(8)))  unsigned short us8;

// ---------------------------------------------------------------------------
// K1: z2/e2 with numpy's exact pairwise structure (proven in R1)
// ---------------------------------------------------------------------------
__global__ void k1_norms(const float* __restrict__ z, const float* __restrict__ w,
                         float* __restrict__ z2, float* __restrict__ e2)
{
#pragma clang fp contract(off)
    int gid = blockIdx.x * blockDim.x + threadIdx.x;
    const float* row;
    float* outp;
    if (gid < N_ROWS) { row = z + (size_t)gid * D_DIM; outp = z2 + gid; }
    else if (gid < N_ROWS + K_CODES) { row = w + (size_t)(gid - N_ROWS) * D_DIM; outp = e2 + (gid - N_ROWS); }
    else return;

    float total = 0.0f;
    for (int half = 0; half < 2; half++) {
        const float* x = row + half * 128;
        float r[8];
#pragma unroll
        for (int j = 0; j < 8; j++) { float v = x[j]; r[j] = v * v; }
        for (int i = 8; i < 128; i += 8) {
#pragma unroll
            for (int j = 0; j < 8; j++) { float v = x[i + j]; r[j] += v * v; }
        }
        float s = ((r[0] + r[1]) + (r[2] + r[3])) + ((r[4] + r[5]) + (r[6] + r[7]));
        if (half == 0) total = s; else total = total + s;
    }
    *outp = total;
}

// ---------------------------------------------------------------------------
// KCONV v2: fp32 -> bf16 (RNE), written in "LDS-image" PANEL layout so that
// k2's staging is a straight contiguous copy (coalesced global_load_lds).
//
// Panel structure: for each 256-row block B and BK=32 window kk, a 16 KB
// panel at ((B*8)+kk)*16384 bytes. Byte offset inside the panel:
//   ((g*2+s)*64 + lane)*16  holds row (B*256 + g*32 + (lane&31)),
//   cols (kk*32 + s*16 + (lane>>5)*8 .. +8) as 8 bf16 (16 B).
// This is byte-identical to what k2's LDS held in R3 -> scores unchanged.
//
// One wave handles 64 rows x one kk window (g-pair aligned). Writes
// coalesce into 4 x (2x512B) runs; reads are 128 B/lane strided (read-once).
// ---------------------------------------------------------------------------
__device__ inline unsigned short f2b(float f) {
    __hip_bfloat16 h = __float2bfloat16(f);
    return *(unsigned short*)&h;
}

__global__ void kconv(const float* __restrict__ z, const float* __restrict__ w,
                      unsigned short* __restrict__ zb, unsigned short* __restrict__ wb)
{
    const int lane  = threadIdx.x & 63;
    const int gwave = blockIdx.x * 4 + (threadIdx.x >> 6);   // 0..4607
    const int kk    = gwave & 7;
    const int row   = (gwave >> 3) * 64 + lane;              // 0..36863
    const float* src;
    unsigned short* panel;
    int g;
    if (row < N_ROWS) {
        src   = z + (size_t)row * D_DIM;
        panel = zb + ((size_t)((row >> 8) * 8 + kk) << 13);  // 8192 ushorts = 16 KB
        g     = (row >> 5) & 7;
    } else {
        int c = row - N_ROWS;
        src   = w + (size_t)c * D_DIM;
        panel = wb + ((size_t)((c >> 8) * 8 + kk) << 13);
        g     = (c >> 5) & 7;
    }
    const int r31 = row & 31;
    const float* s0 = src + kk * 32;
#pragma unroll
    for (int s = 0; s < 2; s++)
#pragma unroll
        for (int h = 0; h < 2; h++) {
            float4 a = *(const float4*)(s0 + s * 16 + h * 8);
            float4 b = *(const float4*)(s0 + s * 16 + h * 8 + 4);
            us8 o;
            o[0] = f2b(a.x); o[1] = f2b(a.y); o[2] = f2b(a.z); o[3] = f2b(a.w);
            o[4] = f2b(b.x); o[5] = f2b(b.y); o[6] = f2b(b.z); o[7] = f2b(b.w);
            *(us8*)(panel + (((g * 2 + s) * 64 + h * 32 + r31) << 3)) = o;
        }
}

// ---------------------------------------------------------------------------
// async global->LDS, 16B per lane. LDS dest = wave-uniform base + lane*16.
// ---------------------------------------------------------------------------
__device__ inline void gload16(const void* g, void* l)
{
    __builtin_amdgcn_global_load_lds(
        (const __attribute__((address_space(1))) unsigned int*)g,
        (__attribute__((address_space(3))) unsigned int*)l,
        16, 0, 0);
}

// ---------------------------------------------------------------------------
// K2 v4: 256x256-tile bf16 MFMA GEMM t = W @ Z^T. Identical math/layout to
// R3 (512 thr = 8 waves 2x4, wave tile 128x64 = acc[4][2], BK=32 dbuf LDS),
// but staging is now a LINEAR COPY of precomputed 16 KB panels:
// each global_load_lds reads 1 KB CONTIGUOUS global (vs 64-way 512B-strided
// scatter before -- the R0..R3 bottleneck: ~2K scattered 16B transactions
// per window serialized the loop at ~31K cyc/window).
//
// Appends once per block vs block-local 256-code row max (proven R3):
// superset of the global-threshold set; packed (key|code) entries let
// k_rescore recover the global bf16 max and re-filter exactly.
//
// XCD-bijective swizzle: all 16 code-blocks of a row-tile on one XCD ->
// cnt/cand atomics XCD-local, zb slice (2MB) + wb (2MB) L2-resident.
// ---------------------------------------------------------------------------
__global__ __launch_bounds__(512, 2) void k2_scan(
    const unsigned short* __restrict__ zb, const unsigned short* __restrict__ wb,
    int* __restrict__ cnt, unsigned int* __restrict__ cand)
{
    __shared__ char smem[65536];
    const int tid  = threadIdx.x;
    const int lane = tid & 63;
    const int wid  = tid >> 6;     // 0..7
    const int wm   = wid >> 2;     // code-wave 0..1
    const int wn   = wid & 3;      // row-wave 0..3
    const int m    = lane & 31;
    const int half = lane >> 5;

    // bijective XCD swizzle: logical o such that XCD(hw_id) == o/256
    const int r_hw = blockIdx.y * 16 + blockIdx.x;
    const int o    = (r_hw & 7) * 256 + (r_hw >> 3);
    const int cb   = o & 15;       // code-block 0..15
    const int rb   = o >> 4;       // row-block  0..127
    const int rowBase  = rb * 256;
    const int codeBase = cb * 256;

    // linear panel copy: A panel (wb) and B panel (zb) for window kk.
    auto stage = [&](int kk, int buf) {
        char* Ab = smem + buf * 32768;
        char* Bb = Ab + 16384;
        const unsigned short* Ap = wb + ((size_t)(cb * 8 + kk) << 13);
        const unsigned short* Bp = zb + ((size_t)(rb * 8 + kk) << 13);
#pragma unroll
        for (int i = 0; i < 2; i++) {
            gload16(Ap + (size_t)((i * 512 + tid) << 3), Ab + (size_t)(i * 512 + tid) * 16);
            gload16(Bp + (size_t)((i * 512 + tid) << 3), Bb + (size_t)(i * 512 + tid) * 16);
        }
    };

    f32x16 acc[4][2];
    {
        f32x16 zz = {};
#pragma unroll
        for (int ms = 0; ms < 4; ms++)
#pragma unroll
            for (int ns = 0; ns < 2; ns++) acc[ms][ns] = zz;
    }

    stage(0, 0);

    for (int kk = 0; kk < 8; kk++) {
        const int buf = kk & 1;
        __syncthreads();                       // drains vmcnt -> buf ready
        if (kk + 1 < 8) stage(kk + 1, buf ^ 1);
        const char* Ab = smem + buf * 32768;
        const char* Bb = Ab + 16384;
#pragma unroll
        for (int s = 0; s < 2; s++) {
            bf16x8 af[4], bfr[2];
#pragma unroll
            for (int ms = 0; ms < 4; ms++)
                af[ms] = *(const bf16x8*)(Ab + (size_t)(((wm * 4 + ms) * 2 + s) * 64 + lane) * 16);
#pragma unroll
            for (int ns = 0; ns < 2; ns++)
                bfr[ns] = *(const bf16x8*)(Bb + (size_t)(((wn * 2 + ns) * 2 + s) * 64 + lane) * 16);
#pragma unroll
            for (int ms = 0; ms < 4; ms++)
#pragma unroll
                for (int ns = 0; ns < 2; ns++)
                    acc[ms][ns] = __builtin_amdgcn_mfma_f32_32x32x16_bf16(
                        af[ms], bfr[ns], acc[ms][ns], 0, 0, 0);
        }
    }

    // ---- epilogue: block-local per-row max over all 256 codes ----
    float tmax[2] = {-1e30f, -1e30f};
#pragma unroll
    for (int ms = 0; ms < 4; ms++)
#pragma unroll
        for (int ns = 0; ns < 2; ns++)
#pragma unroll
            for (int r = 0; r < 16; r++)
                tmax[ns] = fmaxf(tmax[ns], acc[ms][ns][r]);
#pragma unroll
    for (int ns = 0; ns < 2; ns++)
        tmax[ns] = fmaxf(tmax[ns], __shfl_xor(tmax[ns], 32));

    __syncthreads();                 // GEMM LDS dead; reuse for rowmax
    float* rmx = (float*)smem;       // [2][256]: [wm][local row]
    if (lane < 32) {
        rmx[wm * 256 + wn * 64 + 0 * 32 + lane] = tmax[0];
        rmx[wm * 256 + wn * 64 + 1 * 32 + lane] = tmax[1];
    }
    __syncthreads();

    float thr[2];
#pragma unroll
    for (int ns = 0; ns < 2; ns++) {
        const int lr = wn * 64 + ns * 32 + m;
        thr[ns] = fmaxf(rmx[lr], rmx[256 + lr]) - MARGIN_T;
    }

    // ---- append keepers (once per block; atomics XCD-local by swizzle) ----
#pragma unroll
    for (int ms = 0; ms < 4; ms++)
#pragma unroll
        for (int ns = 0; ns < 2; ns++)
#pragma unroll
            for (int r = 0; r < 16; r++) {
                float v = acc[ms][ns][r];
                if (v >= thr[ns]) {
                    int code = codeBase + wm * 128 + ms * 32
                             + ((r & 3) + 8 * (r >> 2) + 4 * half);
                    int n = rowBase + wn * 64 + ns * 32 + m;
                    int b = __float_as_int(v);
                    unsigned key = (unsigned)b ^ ((unsigned)(b >> 31) | 0x80000000u);
                    unsigned entry = (key & 0xFFFFF000u) | (unsigned)code;
                    int slot = atomicAdd(&cnt[n], 1);
                    if (slot < CAP) cand[(size_t)n * CAP + slot] = entry;
                }
            }
}

// ---------------------------------------------------------------------------
// K_RESCORE v5: one WAVE per row.
// Phase A (filter): scan packed entries, wave-reduce max score key (== the
//   global bf16 row max, lower-bounded within 1.5e-5 by the 20-bit key
//   truncation), keep entries with score >= gm - MARGIN - 5e-5 (superset of
//   the proven two-pass candidate set), ballot-compact codes into LDS.
// Phase B: exact fp32 rescore of the few survivors (serial 256-FMA chain,
//   ascending d, single accumulator = bit-identical to BLAS sgemm),
//   lexicographic (d,k) tie-break. Fallback full 4096 scan if cnt out of
//   range (unchanged semantics).
// ---------------------------------------------------------------------------
__global__ __launch_bounds__(64) void k_rescore(
    const float* __restrict__ z, const float* __restrict__ w,
    const float* __restrict__ z2, const float* __restrict__ e2,
    const int* __restrict__ cnt, const unsigned int* __restrict__ cand,
    int* __restrict__ idx_out)
{
#pragma clang fp contract(off)
    const int lane = threadIdx.x;
    const int n    = blockIdx.x;

    __shared__ float4 wst[RB * 65];   // 8320 B, slot j at wst[j*65 + d4]
    __shared__ float4 zst[64];        // z row, 1 KB
    __shared__ int    surv[CAP];      // compacted survivor codes

    zst[lane] = ((const float4*)(z + (size_t)n * D_DIM))[lane];

    int c = cnt[n];
    const bool fallback = (c <= 0) || (c > CAP);
    int total;

    if (!fallback) {
        unsigned e0 = 0u, e1 = 0u;
        if (lane < c)      e0 = cand[(size_t)n * CAP + lane];
        if (lane + 64 < c) e1 = cand[(size_t)n * CAP + lane + 64];
        unsigned k0 = e0 & 0xFFFFF000u, k1 = e1 & 0xFFFFF000u;
        unsigned km = k0 > k1 ? k0 : k1;
#pragma unroll
        for (int off = 32; off > 0; off >>= 1) {
            unsigned o = __shfl_xor(km, off);
            km = o > km ? o : km;
        }
        // lower-bound float of the max key (truncation rounds toward -inf
        // in ordered space), minus margin + quantization slack
        int bm = (km & 0x80000000u) ? (int)(km ^ 0x80000000u) : (int)~km;
        const float thr = __int_as_float(bm) - MARGIN_T - 5e-5f;

        int tot = 0;
        for (int base = 0; base < c; base += 64) {
            unsigned e = (base == 0) ? e0 : e1;
            bool keep = false;
            if (base + lane < c) {
                unsigned ky = e & 0xFFFFF000u;
                int b = (ky & 0x80000000u) ? (int)(ky ^ 0x80000000u) : (int)~ky;
                keep = (__int_as_float(b) >= thr);
            }
            unsigned long long bal = __ballot(keep);
            int pos = tot + (int)__popcll(bal & ((1ull << lane) - 1ull));
            if (keep) surv[pos] = (int)(e & 0xFFFu);
            tot += (int)__popcll(bal);
        }
        total = tot;          // >= 1 (the max-key entry always passes)
    } else {
        total = K_CODES;
    }
    __syncthreads();

    float bd = __builtin_inff(); int bk = K_CODES;
    const float z2v = z2[n];

    float4 regs[RB];
    auto load_regs = [&](int base) {
#pragma unroll
        for (int j = 0; j < RB; j++) {
            int s = base + j;
            int k = 0;
            if (s < total) k = fallback ? s : surv[s];
            regs[j] = ((const float4*)(w + (size_t)k * D_DIM))[lane];
        }
    };

    load_regs(0);
    for (int base = 0; base < total; base += RB) {
        int nb = total - base; if (nb > RB) nb = RB;
#pragma unroll
        for (int j = 0; j < RB; j++) wst[j * 65 + lane] = regs[j];
        if (base + RB < total) load_regs(base + RB);   // prefetch during chain
        __syncthreads();
        if (lane < nb) {
            int k = fallback ? (base + lane) : surv[base + lane];
            const float4* wp = &wst[lane * 65];
            float tacc = 0.0f;
#pragma unroll
            for (int d4 = 0; d4 < 64; d4++) {
                float4 wv = wp[d4];
                float4 zv = zst[d4];
                tacc = __builtin_fmaf(zv.x, wv.x, tacc);
                tacc = __builtin_fmaf(zv.y, wv.y, tacc);
                tacc = __builtin_fmaf(zv.z, wv.z, tacc);
                tacc = __builtin_fmaf(zv.w, wv.w, tacc);
            }
            float u  = z2v - 2.0f * tacc;   // 2*tacc exact -> single rounding
            float dv = u + e2[k];
            if (dv < bd || (dv == bd && k < bk)) { bd = dv; bk = k; }
        }
        __syncthreads();
    }

#pragma unroll
    for (int off = 1; off < 64; off <<= 1) {
        float od = __shfl_xor(bd, off);
        int   ok = __shfl_xor(bk, off);
        if (od < bd || (od == bd && ok < bk)) { bd = od; bk = ok; }
    }
    if (lane == 0) idx_out[n] = bk;
}

// ---------------------------------------------------------------------------
// K3: gather z_q, STE output, loss partials, counts + dw atomics.
// ---------------------------------------------------------------------------
__global__ void k3_scatter(const float* __restrict__ z, const float* __restrict__ w,
                           const int* __restrict__ idx_in,
                           float* __restrict__ counts, float* __restrict__ lossp,
                           float* __restrict__ dw, float* __restrict__ out_zq,
                           float* __restrict__ out_idx)
{
#pragma clang fp contract(off)
    const int n = blockIdx.x;
    const int t = threadIdx.x;
    int idx = idx_in[n];
    if (idx < 0) idx = 0;
    if (idx >= K_CODES) idx = K_CODES - 1;     // defensive clamp (no fault)
    if (t == 0) {
        out_idx[n] = (float)idx;
        atomicAdd(&counts[idx], 1.0f);
    }
    float zv = z[(size_t)n * D_DIM + t];
    float wq = w[(size_t)idx * D_DIM + t];
    out_zq[(size_t)n * D_DIM + t] = zv + (wq - zv);
    float df = zv - wq;
    float sq = df * df;
    atomicAdd(&dw[(size_t)idx * D_DIM + t], zv);

    __shared__ float red[256];
    red[t] = sq; __syncthreads();
    for (int s = 128; s > 0; s >>= 1) {
        if (t < s) red[t] += red[t + s];
        __syncthreads();
    }
    if (t == 0) lossp[n] = red[0];
}

// ---------------------------------------------------------------------------
// K4: vq_loss finalize + new_cs (Laplace smoothing). Single block, 1024 thr.
// ---------------------------------------------------------------------------
__global__ void k4_cs(const float* __restrict__ lossp, const float* __restrict__ counts,
                      const float* __restrict__ cs_in, float* __restrict__ out_loss,
                      float* __restrict__ out_cs)
{
#pragma clang fp contract(off)
    const int t = threadIdx.x;
    __shared__ float red[1024];
    __shared__ float pre[K_CODES];

    float s = 0.0f;
    for (int i = t; i < N_ROWS; i += 1024) s += lossp[i];
    red[t] = s; __syncthreads();
    for (int st = 512; st > 0; st >>= 1) {
        if (t < st) red[t] += red[t + st];
        __syncthreads();
    }
    if (t == 0) out_loss[0] = 0.25f * (red[0] / 8388608.0f);
    __syncthreads();

    const float DEC = 0.99f;
    const float OMD = (float)(1.0 - 0.99);
    float mine[4];
#pragma unroll
    for (int q = 0; q < 4; q++) {
        int k = t + q * 1024;
        float t1 = DEC * cs_in[k];
        float t2 = OMD * counts[k];
        float p = t1 + t2;
        pre[k] = p; mine[q] = p;
    }
    float psum = (mine[0] + mine[1]) + (mine[2] + mine[3]);
    red[t] = psum; __syncthreads();
    for (int st = 512; st > 0; st >>= 1) {
        if (t < st) red[t] += red[t + st];
        __syncthreads();
    }
    float nsum = red[0];
    const float KEPS = (float)(4096.0 * 1e-5);
    float denom = nsum + KEPS;
#pragma unroll
    for (int q = 0; q < 4; q++) {
        int k = t + q * 1024;
        float v = ((pre[k] + 1e-5f) / denom) * nsum;
        out_cs[k] = v;
    }
}

// ---------------------------------------------------------------------------
// K5: new_ema_w = 0.99*ema_w + 0.01*dw ; new_weight = new_ema_w / new_cs[k]
// ---------------------------------------------------------------------------
__global__ void k5_emaw(const float* __restrict__ ema_w, const float* __restrict__ dw,
                        const float* __restrict__ newcs, float* __restrict__ out_w,
                        float* __restrict__ out_emaw)
{
#pragma clang fp contract(off)
    const int i = blockIdx.x * 256 + threadIdx.x;
    const int k = i >> 8;
    const float OMD = (float)(1.0 - 0.99);
    float t1 = 0.99f * ema_w[i];
    float t2 = OMD * dw[i];
    float ne = t1 + t2;
    out_emaw[i] = ne;
    out_w[i] = ne / newcs[k];
}

extern "C" void kernel_launch(void* const* d_in, const int* in_sizes, int n_in,
                              void* d_out, int out_size, void* d_ws, size_t ws_size,
                              hipStream_t stream)
{
    const float* z    = (const float*)d_in[0];
    const float* w    = (const float*)d_in[1];
    const float* cs   = (const float*)d_in[2];
    const float* emaw = (const float*)d_in[3];

    float* out      = (float*)d_out;
    float* out_zq   = out;                    // 8388608
    float* out_idx  = out + 8388608;          // 32768
    float* out_loss = out + 8421376;          // 1
    float* out_w    = out + 8421377;          // 1048576
    float* out_cs   = out + 9469953;          // 4096
    float* out_emaw = out + 9474049;          // 1048576

    char* ws = (char*)d_ws;
    float*          counts  = (float*)(ws + WS_COUNTS);
    float*          lossp   = (float*)(ws + WS_LOSSP);
    int*            idx_int = (int*)  (ws + WS_IDX);
    float*          z2      = (float*)(ws + WS_Z2);
    float*          e2      = (float*)(ws + WS_E2);
    int*            cnt     = (int*)  (ws + WS_CNT);
    float*          dw      = (float*)(ws + WS_DW);

    // big scratch lives in d_out (fully rewritten by k3/k4/k5 afterwards)
    char* ob = (char*)d_out;
    unsigned short* zb   = (unsigned short*)(ob + DO_ZB);
    unsigned short* wb   = (unsigned short*)(ob + DO_WB);
    unsigned int*   cand = (unsigned int*)  (ob + DO_CAND);

    hipMemsetAsync(counts, 0, K_CODES * sizeof(float), stream);
    hipMemsetAsync(dw, 0, (size_t)K_CODES * D_DIM * sizeof(float), stream);
    hipMemsetAsync(cnt, 0, N_ROWS * sizeof(int), stream);

    k1_norms<<<(N_ROWS + K_CODES) / 256, 256, 0, stream>>>(z, w, z2, e2);

    // 4608 waves: (36864 rows / 64 rows-per-wave) * 8 kk-panels; 4 waves/block
    kconv<<<1152, 256, 0, stream>>>(z, w, zb, wb);

    dim3 g2(16, 128);   // x = code-block, y = row-block (swizzled in-kernel)
    k2_scan<<<g2, 512, 0, stream>>>(zb, wb, cnt, cand);

    k_rescore<<<N_ROWS, 64, 0, stream>>>(z, w, z2, e2, cnt, cand, idx_int);

    k3_scatter<<<N_ROWS, 256, 0, stream>>>(z, w, idx_int, counts, lossp,
                                           dw, out_zq, out_idx);

    k4_cs<<<1, 1024, 0, stream>>>(lossp, counts, cs, out_loss, out_cs);

    k5_emaw<<<K_CODES, 256, 0, stream>>>(emaw, dw, out_cs, out_w, out_emaw);
}